// Round 6
// baseline (324.820 us; speedup 1.0000x reference)
//
#include <hip/hip_runtime.h>
#include <stdint.h>
#include <stddef.h>

// Problem constants
#define NV    32000
#define HDIM  512
#define LSRC  320
#define MROWS 1024          // B * L_R
#define SCALEF 0.044194173824159216f   // 1/sqrt(512)

typedef unsigned short u16;
typedef unsigned int   u32;
typedef __attribute__((ext_vector_type(8))) short short8;   // 8 bf16 = 4 VGPRs (MFMA operand)
typedef __attribute__((ext_vector_type(4))) float floatx4;  // MFMA accumulator

// ---- helpers ----------------------------------------------------------------
__device__ __forceinline__ u16 f2bf(float f) {            // f32 -> bf16, RNE
  u32 x = __float_as_uint(f);
  return (u16)((x + 0x7fffu + ((x >> 16) & 1u)) >> 16);
}

typedef __attribute__((address_space(1))) void gvoid;
typedef __attribute__((address_space(3))) void lvoid;
// async global->LDS, 16B/lane; LDS dest = wave-uniform base + lane*16 (m104)
__device__ __forceinline__ void cp16(const u16* g, u16* l) {
  __builtin_amdgcn_global_load_lds((gvoid*)g, (lvoid*)l, 16, 0, 0);
}

// ---- K1: dec_out + src_hidden f32 -> bf16 retile ----------------------------
// blocks [0,256):    dec -> Ab [mt(4)][kt(16)][mi(256)][ki(32)] (+ rowSum=0)
// blocks [256,1024): srch -> Sb [b(8)][st(3)][kt(16)][si(128)][ki(32)], s>=320 zero
// (Ab in 256-row tiles for the gen GEMM; Sb in 128 tiles, batch-aligned, for k_copy)
__global__ __launch_bounds__(256) void k_conv(const float* __restrict__ dec,
                                              const float* __restrict__ srch,
                                              u16* __restrict__ Ab,
                                              u16* __restrict__ Sb,
                                              float* __restrict__ rowSum) {
  if (blockIdx.x < 256) {
    if (blockIdx.x == 0) {
      ((float4*)rowSum)[threadIdx.x] = (float4){0.f, 0.f, 0.f, 0.f};  // 1024 floats
    }
    int t = blockIdx.x * 256 + threadIdx.x;     // 65536 threads, 8 elems each
    int o = t * 8;
    int ki = o & 31;
    int mi = (o >> 5) & 255;
    int kt = (o >> 13) & 15;
    int mt = o >> 17;                            // 4 m-tiles of 256 rows
    const float* s = dec + (size_t)(mt * 256 + mi) * HDIM + kt * 32 + ki;
    float4 a = ((const float4*)s)[0];
    float4 b = ((const float4*)s)[1];
    union { u16 h[8]; uint4 v; } pk;
    pk.h[0] = f2bf(a.x); pk.h[1] = f2bf(a.y); pk.h[2] = f2bf(a.z); pk.h[3] = f2bf(a.w);
    pk.h[4] = f2bf(b.x); pk.h[5] = f2bf(b.y); pk.h[6] = f2bf(b.z); pk.h[7] = f2bf(b.w);
    *(uint4*)(Ab + o) = pk.v;
  } else {
    int t = (blockIdx.x - 256) * 256 + threadIdx.x;   // 196608 threads, 8 elems
    int o = t * 8;
    int ki = o & 31;
    int ni = (o >> 5) & 127;
    int kt = (o >> 12) & 15;
    int r  = o >> 16;                          // b*3 + st
    int st = r % 3, b = r / 3;
    int s = st * 128 + ni;
    uint4 v;
    if (s < LSRC) {
      const float* p = srch + ((size_t)b * LSRC + s) * HDIM + kt * 32 + ki;
      float4 a = ((const float4*)p)[0];
      float4 c = ((const float4*)p)[1];
      union { u16 h[8]; uint4 u; } pk;
      pk.h[0] = f2bf(a.x); pk.h[1] = f2bf(a.y); pk.h[2] = f2bf(a.z); pk.h[3] = f2bf(a.w);
      pk.h[4] = f2bf(c.x); pk.h[5] = f2bf(c.y); pk.h[6] = f2bf(c.z); pk.h[7] = f2bf(c.w);
      v = pk.u;
    } else {
      v = (uint4){0u, 0u, 0u, 0u};
    }
    *(uint4*)(Sb + o) = v;
  }
}

// ---- K2: W_gen f32 [k][n] -> bf16 tiled [nt(125)][kt(16)][ni(256)][ki(32)] --
// (transpose k<->n inner order via LDS; stride 36 breaks bank conflicts)
__global__ __launch_bounds__(256) void k_convW(const float* __restrict__ W,
                                               u16* __restrict__ Wb) {
  __shared__ u16 lds[256 * 36];            // 18 KiB
  int tileId = blockIdx.x;                 // 0..1999 = nt*16 + kt
  int nt = tileId >> 4, kt = tileId & 15;
  int t = threadIdx.x;
  const float* src = W + (size_t)kt * 32 * NV + (size_t)nt * 256;
#pragma unroll
  for (int i = 0; i < 8; ++i) {
    int f = t + 256 * i;                   // float4 id, 0..2047
    int kin = f >> 6, n4 = f & 63;         // coalesced float4 reads along n
    float4 v = *(const float4*)(src + (size_t)kin * NV + n4 * 4);
    int base = (n4 * 4) * 36 + kin;
    lds[base]       = f2bf(v.x);
    lds[base + 36]  = f2bf(v.y);
    lds[base + 72]  = f2bf(v.z);
    lds[base + 108] = f2bf(v.w);
  }
  __syncthreads();
  u16* dst = Wb + (size_t)tileId * 8192;
#pragma unroll
  for (int j = 0; j < 4; ++j) {
    int o = t * 8 + j * 2048;              // coalesced 16B writes
    int ni = o >> 5, ki0 = o & 31;
    const u16* p = &lds[ni * 36 + ki0];
    uint2 x = *(const uint2*)p;
    uint2 y = *(const uint2*)(p + 4);
    uint4 v; v.x = x.x; v.y = x.y; v.z = y.x; v.w = y.y;
    *(uint4*)(dst + o) = v;
  }
}

// ---- K3: gen GEMM 1024 x 32000 x 512 bf16 MFMA, 256x256 tiles ---------------
// 256x256 tile (halves per-CU VMEM delivery vs 128^2), BK=32, 8 waves (2m x 4n),
// 3-ring LDS (96 KiB), prefetch distance 2, counted vmcnt(4) (r3/r4 schedule).
// Grid 500 = 4 m-tiles x 125 n-tiles, bijective XCD swizzle (m204: q=62, r=4).
__global__ __launch_bounds__(512, 2) void k_gemm(const u16* __restrict__ Ab,
                                                 const u16* __restrict__ Wb,
                                                 const float* __restrict__ bgen,
                                                 u16* __restrict__ wsE,
                                                 float* __restrict__ rowSum) {
  __shared__ u16 As[3][8192];   // [buf][mi*32+ki]  16 KiB each
  __shared__ u16 Bs[3][8192];   // [buf][ni*32+ki]
  int bid = blockIdx.x;                    // 500
  // bijective XCD swizzle: nwg=500, q=62, r=4 -> same-y blocks on one XCD
  int xcd = bid & 7, rem = bid >> 3;
  int wgid = (xcd < 4 ? xcd * 63 : 252 + (xcd - 4) * 62) + rem;
  int x = wgid & 3, y = wgid >> 2;         // m-tile [0,4), n-tile [0,125)
  int t = threadIdx.x;
  int wid = t >> 6, lane = t & 63;
  int wm = wid >> 2, wn = wid & 3;         // 2x4 waves over 256x256 tile
  int quad = lane >> 4, l16 = lane & 15;

  const u16* At = Ab + (size_t)x * (16 * 8192);
  const u16* Bt = Wb + (size_t)y * (16 * 8192);
  // staging: each wave stages 2x 512-u16 chunks of each A/B K-slab
  const u16* Ag0 = At + wid * 512 + lane * 8;
  const u16* Bg0 = Bt + wid * 512 + lane * 8;

  floatx4 acc[8][4];
#pragma unroll
  for (int i = 0; i < 8; ++i)
#pragma unroll
    for (int j = 0; j < 4; ++j) acc[i][j] = (floatx4){0.f, 0.f, 0.f, 0.f};

  // prologue: stage kt=0 and kt=1 into bufs 0,1 (8 VMEM instr in flight)
#pragma unroll
  for (int p = 0; p < 2; ++p) {
    const u16* ag = Ag0 + p * 8192;
    const u16* bg = Bg0 + p * 8192;
    cp16(ag,        &As[p][wid * 512]);
    cp16(ag + 4096, &As[p][wid * 512 + 4096]);
    cp16(bg,        &Bs[p][wid * 512]);
    cp16(bg + 4096, &Bs[p][wid * 512 + 4096]);
  }

#pragma unroll
  for (int kt = 0; kt < 16; ++kt) {
    const int cb = kt % 3;                  // compile-time (unrolled)
    asm volatile("s_waitcnt lgkmcnt(0)" ::: "memory");
    if (kt < 15) asm volatile("s_waitcnt vmcnt(4)" ::: "memory");
    else         asm volatile("s_waitcnt vmcnt(0)" ::: "memory");
    __builtin_amdgcn_s_barrier();           // all waves' buf-kt stages done
    asm volatile("" ::: "memory");
    if (kt < 14) {                          // stage kt+2 into buf (kt+2)%3
      const int sb = (kt + 2) % 3;
      const u16* ag = Ag0 + (kt + 2) * 8192;
      const u16* bg = Bg0 + (kt + 2) * 8192;
      cp16(ag,        &As[sb][wid * 512]);
      cp16(ag + 4096, &As[sb][wid * 512 + 4096]);
      cp16(bg,        &Bs[sb][wid * 512]);
      cp16(bg + 4096, &Bs[sb][wid * 512 + 4096]);
    }
    short8 aR[8], bR[4];
#pragma unroll
    for (int mt = 0; mt < 8; ++mt)
      aR[mt] = *(const short8*)&As[cb][(wm * 128 + mt * 16 + l16) * 32 + quad * 8];
#pragma unroll
    for (int nt = 0; nt < 4; ++nt)
      bR[nt] = *(const short8*)&Bs[cb][(wn * 64 + nt * 16 + l16) * 32 + quad * 8];
    __builtin_amdgcn_s_setprio(1);
#pragma unroll
    for (int mt = 0; mt < 8; ++mt)
#pragma unroll
      for (int nt = 0; nt < 4; ++nt)
        acc[mt][nt] = __builtin_amdgcn_mfma_f32_16x16x32_bf16(bR[nt], aR[mt],
                                                              acc[mt][nt], 0, 0, 0);
    __builtin_amdgcn_s_setprio(0);
  }

  // Swapped-D layout: row m = row0 + mt*16 + l16 (lane-local),
  //                   cols n = col0 + nt*16 + quad*4 + r (4 consecutive)
  int row0 = x * 256 + wm * 128;
  int col0 = y * 256 + wn * 64;
  float bq[4][4];                          // bias*SCALEF, [nt][r], quad-broadcast
#pragma unroll
  for (int nt = 0; nt < 4; ++nt) {
    float4 v = *(const float4*)(bgen + col0 + nt * 16 + quad * 4);
    bq[nt][0] = v.x * SCALEF; bq[nt][1] = v.y * SCALEF;
    bq[nt][2] = v.z * SCALEF; bq[nt][3] = v.w * SCALEF;
  }
#pragma unroll
  for (int mt = 0; mt < 8; ++mt) {
    int row = row0 + mt * 16 + l16;
    float rsum = 0.f;
#pragma unroll
    for (int nt = 0; nt < 4; ++nt) {
      float e0 = __expf(fmaf(acc[mt][nt][0], SCALEF, bq[nt][0]));
      float e1 = __expf(fmaf(acc[mt][nt][1], SCALEF, bq[nt][1]));
      float e2 = __expf(fmaf(acc[mt][nt][2], SCALEF, bq[nt][2]));
      float e3 = __expf(fmaf(acc[mt][nt][3], SCALEF, bq[nt][3]));
      uint2 pk;
      pk.x = (u32)f2bf(e0) | ((u32)f2bf(e1) << 16);
      pk.y = (u32)f2bf(e2) | ((u32)f2bf(e3) << 16);
      *(uint2*)(wsE + (size_t)row * NV + col0 + nt * 16 + quad * 4) = pk;
      rsum += (e0 + e1) + (e2 + e3);
    }
    rsum += __shfl_xor(rsum, 16, 64);
    rsum += __shfl_xor(rsum, 32, 64);
    if (lane < 16) atomicAdd(&rowSum[row], rsum);
  }
}

// ---- K4: copy GEMM (batch-aligned 128x128, r4-verified structure) -----------
// Grid 24 = 8 batches x 3 s-tiles. A = batch's 128-row half of the 256-layout
// Ab (contiguous 4096-u16 half-slab). B = Sb 128-tile. Masked f32 exp ->wsCopy.
__global__ __launch_bounds__(256) void k_copy(const u16* __restrict__ Ab,
                                              const u16* __restrict__ Sb,
                                              const int* __restrict__ mask,
                                              float* __restrict__ wsCopy,
                                              float* __restrict__ rowSum) {
  __shared__ u16 As[3][4096];   // [buf][mi*32+ki]  8 KiB each
  __shared__ u16 Bs[3][4096];
  int bid = blockIdx.x;                    // b*3 + st
  int b = bid / 3, st = bid % 3;
  int t = threadIdx.x;
  int wid = t >> 6, lane = t & 63;
  int wm = wid >> 1, wn = wid & 1;         // 2x2 waves over 128x128 tile
  int quad = lane >> 4, l16 = lane & 15;

  // batch b's rows live in Ab tile (b>>1), rows [(b&1)*128, (b&1)*128+128)
  const u16* At = Ab + (size_t)(b >> 1) * (16 * 8192) + (b & 1) * 4096;
  const u16* Bt = Sb + (size_t)(b * 3 + st) * (16 * 4096);
  const u16* Ag0 = At + wid * 1024 + lane * 8;   // A slab stride 8192!
  const u16* Bg0 = Bt + wid * 1024 + lane * 8;   // B slab stride 4096

  floatx4 acc[4][4];
#pragma unroll
  for (int i = 0; i < 4; ++i)
#pragma unroll
    for (int j = 0; j < 4; ++j) acc[i][j] = (floatx4){0.f, 0.f, 0.f, 0.f};

#pragma unroll
  for (int p = 0; p < 2; ++p) {
    const u16* ag = Ag0 + p * 8192;
    const u16* bg = Bg0 + p * 4096;
    cp16(ag,       &As[p][wid * 1024]);
    cp16(ag + 512, &As[p][wid * 1024 + 512]);
    cp16(bg,       &Bs[p][wid * 1024]);
    cp16(bg + 512, &Bs[p][wid * 1024 + 512]);
  }

#pragma unroll
  for (int kt = 0; kt < 16; ++kt) {
    const int cb = kt % 3;
    asm volatile("s_waitcnt lgkmcnt(0)" ::: "memory");
    if (kt < 15) asm volatile("s_waitcnt vmcnt(4)" ::: "memory");
    else         asm volatile("s_waitcnt vmcnt(0)" ::: "memory");
    __builtin_amdgcn_s_barrier();
    asm volatile("" ::: "memory");
    if (kt < 14) {
      const int sb = (kt + 2) % 3;
      const u16* ag = Ag0 + (kt + 2) * 8192;
      const u16* bg = Bg0 + (kt + 2) * 4096;
      cp16(ag,       &As[sb][wid * 1024]);
      cp16(ag + 512, &As[sb][wid * 1024 + 512]);
      cp16(bg,       &Bs[sb][wid * 1024]);
      cp16(bg + 512, &Bs[sb][wid * 1024 + 512]);
    }
    short8 aR[4], bR[4];
#pragma unroll
    for (int mt = 0; mt < 4; ++mt)
      aR[mt] = *(const short8*)&As[cb][(wm * 64 + mt * 16 + l16) * 32 + quad * 8];
#pragma unroll
    for (int nt = 0; nt < 4; ++nt)
      bR[nt] = *(const short8*)&Bs[cb][(wn * 64 + nt * 16 + l16) * 32 + quad * 8];
#pragma unroll
    for (int mt = 0; mt < 4; ++mt)
#pragma unroll
      for (int nt = 0; nt < 4; ++nt)
        acc[mt][nt] = __builtin_amdgcn_mfma_f32_16x16x32_bf16(bR[nt], aR[mt],
                                                              acc[mt][nt], 0, 0, 0);
  }

  int row0 = b * 128 + wm * 64;
  int sBase = st * 128 + wn * 64;
  if (sBase < LSRC) {                      // wave-uniform; st=2,wn=1 is all-pad
    int mq[4][4];                          // mask, [nt][r], quad-broadcast
#pragma unroll
    for (int nt = 0; nt < 4; ++nt) {
      int4 v = *(const int4*)(mask + b * LSRC + sBase + nt * 16 + quad * 4);
      mq[nt][0] = v.x; mq[nt][1] = v.y; mq[nt][2] = v.z; mq[nt][3] = v.w;
    }
#pragma unroll
    for (int mt = 0; mt < 4; ++mt) {
      int row = row0 + mt * 16 + l16;
      float rsum = 0.f;
#pragma unroll
      for (int nt = 0; nt < 4; ++nt) {
        float4 ev;
        ev.x = mq[nt][0] ? __expf(acc[mt][nt][0] * SCALEF) : 0.f;
        ev.y = mq[nt][1] ? __expf(acc[mt][nt][1] * SCALEF) : 0.f;
        ev.z = mq[nt][2] ? __expf(acc[mt][nt][2] * SCALEF) : 0.f;
        ev.w = mq[nt][3] ? __expf(acc[mt][nt][3] * SCALEF) : 0.f;
        *(float4*)(wsCopy + (size_t)row * LSRC + sBase + nt * 16 + quad * 4) = ev;
        rsum += (ev.x + ev.y) + (ev.z + ev.w);
      }
      rsum += __shfl_xor(rsum, 16, 64);
      rsum += __shfl_xor(rsum, 32, 64);
      if (lane < 16) atomicAdd(&rowSum[row], rsum);
    }
  }
}

// ---- K5: normalize + scatter (one block owns one output row, 512 thr) -------
__global__ __launch_bounds__(512) void k_norm(const u16* __restrict__ wsE,
                                              const float* __restrict__ wsCopy,
                                              const float* __restrict__ rowSum,
                                              const int* __restrict__ context,
                                              const int* __restrict__ tp,
                                              const int* __restrict__ action,
                                              const int* __restrict__ loc2glo,
                                              float* __restrict__ out) {
  int r = blockIdx.x, b = r >> 7;
  float inv = 1.0f / rowSum[r];
  const uint2* src = (const uint2*)(wsE + (size_t)r * NV);
  float4* dst = (float4*)(out + (size_t)r * NV);
  for (int c = threadIdx.x; c < NV / 4; c += 512) {
    uint2 v = src[c];
    float4 o;
    o.x = __uint_as_float(v.x << 16) * inv;
    o.y = __uint_as_float(v.x & 0xffff0000u) * inv;
    o.z = __uint_as_float(v.y << 16) * inv;
    o.w = __uint_as_float(v.y & 0xffff0000u) * inv;
    dst[c] = o;
  }
  __syncthreads();   // drains stores (vmcnt) so atomics below see them at L2
  int t = threadIdx.x;
  float* op = out + (size_t)r * NV;
  if (t < 256) {
    atomicAdd(op + context[b * 256 + t], wsCopy[r * LSRC + t] * inv);
  } else if (t < 288) {
    int i = t - 256;
    atomicAdd(op + loc2glo[tp[b * 32 + i]], wsCopy[r * LSRC + 256 + i] * inv);
  } else if (t < 320) {
    int i = t - 288;
    atomicAdd(op + loc2glo[action[b * 32 + i]], wsCopy[r * LSRC + 288 + i] * inv);
  }
}

// ---- launch -----------------------------------------------------------------
extern "C" void kernel_launch(void* const* d_in, const int* in_sizes, int n_in,
                              void* d_out, int out_size, void* d_ws, size_t ws_size,
                              hipStream_t stream) {
  const float* dec  = (const float*)d_in[0];
  const float* srch = (const float*)d_in[1];
  const float* Wg   = (const float*)d_in[2];
  const float* bg   = (const float*)d_in[3];
  const int*   mask = (const int*)d_in[4];
  const int*   ctx  = (const int*)d_in[5];
  const int*   tp   = (const int*)d_in[6];
  const int*   act  = (const int*)d_in[7];
  const int*   l2g  = (const int*)d_in[8];
  float* out = (float*)d_out;

  char* ws = (char*)d_ws;
  // ws layout (bytes):
  u16*   Wb      = (u16*)(ws);                    // 32,768,000  bf16 W tiled (125 tiles)
  u16*   wsE     = (u16*)(ws + 32768000);         // 65,536,000  bf16 exp(gen)
  u16*   Ab      = (u16*)(ws + 98304000);         //  1,048,576  bf16 A tiled (4x256 tiles)
  float* wsCopy  = (float*)(ws + 99352576);       //  1,310,720  fp32 exp(copy)
  float* rowSum  = (float*)(ws + 100663296);      //      4,096  fp32 row sums
  u16*   Sb      = (u16*)(ws + 100667392);        //  3,145,728  bf16 srch tiled (8x3x128)

  hipLaunchKernelGGL(k_conv, dim3(1024), dim3(256), 0, stream, dec, srch, Ab, Sb, rowSum);
  hipLaunchKernelGGL(k_convW, dim3(2000), dim3(256), 0, stream, Wg, Wb);
  hipLaunchKernelGGL(k_gemm, dim3(500), dim3(512), 0, stream, Ab, Wb, bg, wsE, rowSum);
  hipLaunchKernelGGL(k_copy, dim3(24), dim3(256), 0, stream, Ab, Sb, mask, wsCopy, rowSum);
  hipLaunchKernelGGL(k_norm, dim3(MROWS), dim3(512), 0, stream, wsE, wsCopy, rowSum,
                     ctx, tp, act, l2g, out);
}

// Round 7
// 313.266 us; speedup vs baseline: 1.0369x; 1.0369x over previous
//
#include <hip/hip_runtime.h>
#include <stdint.h>
#include <stddef.h>

// Problem constants
#define NV    32000
#define HDIM  512
#define LSRC  320
#define MROWS 1024          // B * L_R
#define SCALEF 0.044194173824159216f   // 1/sqrt(512)

typedef unsigned short u16;
typedef unsigned int   u32;
typedef __attribute__((ext_vector_type(8))) short short8;   // 8 bf16 = 4 VGPRs (MFMA operand)
typedef __attribute__((ext_vector_type(4))) float floatx4;  // MFMA accumulator

// ---- helpers ----------------------------------------------------------------
__device__ __forceinline__ u16 f2bf(float f) {            // f32 -> bf16, RNE
  u32 x = __float_as_uint(f);
  return (u16)((x + 0x7fffu + ((x >> 16) & 1u)) >> 16);
}

typedef __attribute__((address_space(1))) void gvoid;
typedef __attribute__((address_space(3))) void lvoid;
// async global->LDS, 16B/lane; LDS dest = wave-uniform base + lane*16 (m104)
__device__ __forceinline__ void cp16(const u16* g, u16* l) {
  __builtin_amdgcn_global_load_lds((gvoid*)g, (lvoid*)l, 16, 0, 0);
}
#define BARRIER() do { __builtin_amdgcn_s_barrier(); asm volatile("" ::: "memory"); } while (0)

// ---- K1: dec_out + src_hidden f32 -> bf16 retile ----------------------------
// blocks [0,256):    dec -> Ab [mt(4)][kt(16)][mi(256)][ki(32)] (+ rowSum=0)
// blocks [256,1024): srch -> Sb [x(4)][yt(3)][kt(16)][ni(256)][ki(32)]
//   block-diagonal copy layout: col c in [0,768): c<320 -> batch 2x, s=c;
//   320<=c<640 -> batch 2x+1, s=c-320; else zero pad.
__global__ __launch_bounds__(256) void k_conv(const float* __restrict__ dec,
                                              const float* __restrict__ srch,
                                              u16* __restrict__ Ab,
                                              u16* __restrict__ Sb,
                                              float* __restrict__ rowSum) {
  if (blockIdx.x < 256) {
    if (blockIdx.x == 0) {
      ((float4*)rowSum)[threadIdx.x] = (float4){0.f, 0.f, 0.f, 0.f};  // 1024 floats
    }
    int t = blockIdx.x * 256 + threadIdx.x;     // 65536 threads, 8 elems each
    int o = t * 8;
    int ki = o & 31;
    int mi = (o >> 5) & 255;
    int kt = (o >> 13) & 15;
    int mt = o >> 17;                            // 4 m-tiles of 256 rows
    const float* s = dec + (size_t)(mt * 256 + mi) * HDIM + kt * 32 + ki;
    float4 a = ((const float4*)s)[0];
    float4 b = ((const float4*)s)[1];
    union { u16 h[8]; uint4 v; } pk;
    pk.h[0] = f2bf(a.x); pk.h[1] = f2bf(a.y); pk.h[2] = f2bf(a.z); pk.h[3] = f2bf(a.w);
    pk.h[4] = f2bf(b.x); pk.h[5] = f2bf(b.y); pk.h[6] = f2bf(b.z); pk.h[7] = f2bf(b.w);
    *(uint4*)(Ab + o) = pk.v;
  } else {
    int t = (blockIdx.x - 256) * 256 + threadIdx.x;   // 196608 threads, 8 elems
    int o = t * 8;
    int ki = o & 31;
    int ni = (o >> 5) & 255;
    int kt = (o >> 13) & 15;
    int r  = o >> 17;                          // x*3 + yt
    int yt = r % 3, x = r / 3;
    int c = yt * 256 + ni;                     // col within 768-span
    int b, s, valid;
    if (c < 320)      { b = x * 2;     s = c;       valid = 1; }
    else if (c < 640) { b = x * 2 + 1; s = c - 320; valid = 1; }
    else              { b = 0; s = 0; valid = 0; }
    uint4 v;
    if (valid) {
      const float* p = srch + ((size_t)b * LSRC + s) * HDIM + kt * 32 + ki;
      float4 a = ((const float4*)p)[0];
      float4 cc = ((const float4*)p)[1];
      union { u16 h[8]; uint4 u; } pk;
      pk.h[0] = f2bf(a.x);  pk.h[1] = f2bf(a.y);  pk.h[2] = f2bf(a.z);  pk.h[3] = f2bf(a.w);
      pk.h[4] = f2bf(cc.x); pk.h[5] = f2bf(cc.y); pk.h[6] = f2bf(cc.z); pk.h[7] = f2bf(cc.w);
      v = pk.u;
    } else {
      v = (uint4){0u, 0u, 0u, 0u};
    }
    *(uint4*)(Sb + o) = v;
  }
}

// ---- K2: W_gen f32 [k][n] -> bf16 tiled [nt(125)][kt(16)][ni(256)][ki(32)] --
// (transpose k<->n inner order via LDS; stride 36 breaks bank conflicts)
__global__ __launch_bounds__(256) void k_convW(const float* __restrict__ W,
                                               u16* __restrict__ Wb) {
  __shared__ u16 lds[256 * 36];            // 18 KiB
  int tileId = blockIdx.x;                 // 0..1999 = nt*16 + kt
  int nt = tileId >> 4, kt = tileId & 15;
  int t = threadIdx.x;
  const float* src = W + (size_t)kt * 32 * NV + (size_t)nt * 256;
#pragma unroll
  for (int i = 0; i < 8; ++i) {
    int f = t + 256 * i;                   // float4 id, 0..2047
    int kin = f >> 6, n4 = f & 63;         // coalesced float4 reads along n
    float4 v = *(const float4*)(src + (size_t)kin * NV + n4 * 4);
    int base = (n4 * 4) * 36 + kin;
    lds[base]       = f2bf(v.x);
    lds[base + 36]  = f2bf(v.y);
    lds[base + 72]  = f2bf(v.z);
    lds[base + 108] = f2bf(v.w);
  }
  __syncthreads();
  u16* dst = Wb + (size_t)tileId * 8192;
#pragma unroll
  for (int j = 0; j < 4; ++j) {
    int o = t * 8 + j * 2048;              // coalesced 16B writes
    int ni = o >> 5, ki0 = o & 31;
    const u16* p = &lds[ni * 36 + ki0];
    uint2 x = *(const uint2*)p;
    uint2 y = *(const uint2*)(p + 4);
    uint4 v; v.x = x.x; v.y = x.y; v.z = y.x; v.w = y.y;
    *(uint4*)(dst + o) = v;
  }
}

// ---- K3: fused GEMM 1024 x (32000 gen + 768 copy) x 512, fine-phase ---------
// 256x256 tile, 8 waves (2m x 4n), 16 K-slabs of 32. 4-slot LDS ring (128 KiB),
// prefetch depth 3, 2 sub-phases per slab (m201-style interleave):
//   phase = { ds_read frags ; issue 2 global_load_lds (slab h+3) ; barrier ;
//             lgkmcnt(0) ; setprio(1) ; 16 MFMA ; setprio(0) ; barrier }
// Counted vmcnt(8) once per slab (never 0 in steady state); drain 8->4->0.
// Race-free: slab h reads slot h&3, stages slot (h+3)&3 = (h-1)&3 whose reads
// were retired by each wave's lgkmcnt(0) before the preceding barrier.
// Grid 512 = 4 m-tiles x 128 n-tiles. y<125: gen (Wb, +bias, bf16 -> wsE).
// y in {125,126,127}: copy (block-diagonal Sb; batch = 2x+wm is wave-uniform;
// valid col span = [wm*320, wm*320+320) within the 768-col region).
__global__ __launch_bounds__(512, 2) void k_gemm(const u16* __restrict__ Ab,
                                                 const u16* __restrict__ Wb,
                                                 const u16* __restrict__ Sb,
                                                 const float* __restrict__ bgen,
                                                 const int* __restrict__ mask,
                                                 u16* __restrict__ wsE,
                                                 float* __restrict__ wsCopy,
                                                 float* __restrict__ rowSum) {
  __shared__ u16 As[4][8192];   // [slot][mi*32+ki]  16 KiB each (64 KiB)
  __shared__ u16 Bs[4][8192];   // [slot][ni*32+ki]  (64 KiB)
  int bid = blockIdx.x;                    // 512 = 64 per XCD
  int xcd = bid & 7;
  int wgid = xcd * 64 + (bid >> 3);        // same-y (4 blocks) contiguous per XCD
  int x = wgid & 3, y = wgid >> 2;         // m-tile [0,4), n-tile [0,128)
  int t = threadIdx.x;
  int wid = t >> 6, lane = t & 63;
  int wm = wid >> 2, wn = wid & 3;         // 2x4 waves over 256x256 tile
  int quad = lane >> 4, l16 = lane & 15;

  const u16* At = Ab + (size_t)x * (16 * 8192);
  const u16* Bt = (y < 125) ? (Wb + (size_t)y * (16 * 8192))
                            : (Sb + (size_t)(x * 3 + (y - 125)) * (16 * 8192));
  const u16* Ag0 = At + wid * 512 + lane * 8;   // wave stages 1 KiB per cp16
  const u16* Bg0 = Bt + wid * 512 + lane * 8;

  floatx4 acc[8][4];
#pragma unroll
  for (int i = 0; i < 8; ++i)
#pragma unroll
    for (int j = 0; j < 4; ++j) acc[i][j] = (floatx4){0.f, 0.f, 0.f, 0.f};

  // prologue: stage slabs 0,1,2 (12 cp16 in flight)
#pragma unroll
  for (int p = 0; p < 3; ++p) {
    const u16* ag = Ag0 + p * 8192;
    const u16* bg = Bg0 + p * 8192;
    cp16(ag,        &As[p][wid * 512]);
    cp16(ag + 4096, &As[p][wid * 512 + 4096]);
    cp16(bg,        &Bs[p][wid * 512]);
    cp16(bg + 4096, &Bs[p][wid * 512 + 4096]);
  }
  asm volatile("s_waitcnt vmcnt(8)" ::: "memory");  // slab 0 resident
  BARRIER();

#pragma unroll
  for (int h = 0; h < 16; ++h) {
    const int slot = h & 3;
    const int ps = (h + 3) & 3;            // prefetch slot
    const u16* ag = Ag0 + (h + 3) * 8192;
    const u16* bg = Bg0 + (h + 3) * 8192;
    // ---------------- phase A: mt 0-3 ----------------
    short8 aR[4], bR[4];
#pragma unroll
    for (int mt = 0; mt < 4; ++mt)
      aR[mt] = *(const short8*)&As[slot][(wm * 128 + mt * 16 + l16) * 32 + quad * 8];
#pragma unroll
    for (int nt = 0; nt < 4; ++nt)
      bR[nt] = *(const short8*)&Bs[slot][(wn * 64 + nt * 16 + l16) * 32 + quad * 8];
    if (h < 13) {
      cp16(ag, &As[ps][wid * 512]);
      cp16(bg, &Bs[ps][wid * 512]);
    }
    BARRIER();
    asm volatile("s_waitcnt lgkmcnt(0)" ::: "memory");
    __builtin_amdgcn_s_setprio(1);
#pragma unroll
    for (int mt = 0; mt < 4; ++mt)
#pragma unroll
      for (int nt = 0; nt < 4; ++nt)
        acc[mt][nt] = __builtin_amdgcn_mfma_f32_16x16x32_bf16(bR[nt], aR[mt],
                                                              acc[mt][nt], 0, 0, 0);
    __builtin_amdgcn_s_setprio(0);
    BARRIER();
    // ---------------- phase B: mt 4-7 ----------------
#pragma unroll
    for (int mt = 0; mt < 4; ++mt)
      aR[mt] = *(const short8*)&As[slot][(wm * 128 + (mt + 4) * 16 + l16) * 32 + quad * 8];
    if (h < 13) {
      cp16(ag + 4096, &As[ps][wid * 512 + 4096]);
      cp16(bg + 4096, &Bs[ps][wid * 512 + 4096]);
    }
    if (h < 13)      asm volatile("s_waitcnt vmcnt(8)" ::: "memory");
    else if (h == 13) asm volatile("s_waitcnt vmcnt(4)" ::: "memory");
    else             asm volatile("s_waitcnt vmcnt(0)" ::: "memory");
    BARRIER();
    asm volatile("s_waitcnt lgkmcnt(0)" ::: "memory");
    __builtin_amdgcn_s_setprio(1);
#pragma unroll
    for (int mt = 0; mt < 4; ++mt)
#pragma unroll
      for (int nt = 0; nt < 4; ++nt)
        acc[mt + 4][nt] = __builtin_amdgcn_mfma_f32_16x16x32_bf16(bR[nt], aR[mt],
                                                                  acc[mt + 4][nt], 0, 0, 0);
    __builtin_amdgcn_s_setprio(0);
    BARRIER();
  }

  // Swapped-D layout: row m = row0 + mt*16 + l16 (lane-local),
  //                   cols n = col0 + nt*16 + quad*4 + r (4 consecutive)
  int row0 = x * 256 + wm * 128;
  if (y < 125) {
    int col0 = y * 256 + wn * 64;
    float bq[4][4];                        // bias*SCALEF, [nt][r], quad-broadcast
#pragma unroll
    for (int nt = 0; nt < 4; ++nt) {
      float4 v = *(const float4*)(bgen + col0 + nt * 16 + quad * 4);
      bq[nt][0] = v.x * SCALEF; bq[nt][1] = v.y * SCALEF;
      bq[nt][2] = v.z * SCALEF; bq[nt][3] = v.w * SCALEF;
    }
#pragma unroll
    for (int mt = 0; mt < 8; ++mt) {
      int row = row0 + mt * 16 + l16;
      float rsum = 0.f;
#pragma unroll
      for (int nt = 0; nt < 4; ++nt) {
        float e0 = __expf(fmaf(acc[mt][nt][0], SCALEF, bq[nt][0]));
        float e1 = __expf(fmaf(acc[mt][nt][1], SCALEF, bq[nt][1]));
        float e2 = __expf(fmaf(acc[mt][nt][2], SCALEF, bq[nt][2]));
        float e3 = __expf(fmaf(acc[mt][nt][3], SCALEF, bq[nt][3]));
        uint2 pk;
        pk.x = (u32)f2bf(e0) | ((u32)f2bf(e1) << 16);
        pk.y = (u32)f2bf(e2) | ((u32)f2bf(e3) << 16);
        *(uint2*)(wsE + (size_t)row * NV + col0 + nt * 16 + quad * 4) = pk;
        rsum += (e0 + e1) + (e2 + e3);
      }
      rsum += __shfl_xor(rsum, 16, 64);
      rsum += __shfl_xor(rsum, 32, 64);
      if (lane < 16) atomicAdd(&rowSum[row], rsum);
    }
  } else {
    int b = x * 2 + wm;                    // wave-uniform batch
    int sOff = wm * 320;                   // valid col span within 768
    int mq[4][4], vq[4], sc[4];
#pragma unroll
    for (int nt = 0; nt < 4; ++nt) {
      int cc = (y - 125) * 256 + wn * 64 + nt * 16 + quad * 4;
      vq[nt] = (cc >= sOff) && (cc < sOff + 320);
      sc[nt] = cc - sOff;
      if (vq[nt]) {
        int4 v = *(const int4*)(mask + b * LSRC + sc[nt]);
        mq[nt][0] = v.x; mq[nt][1] = v.y; mq[nt][2] = v.z; mq[nt][3] = v.w;
      } else {
        mq[nt][0] = mq[nt][1] = mq[nt][2] = mq[nt][3] = 0;
      }
    }
#pragma unroll
    for (int mt = 0; mt < 8; ++mt) {
      int row = row0 + mt * 16 + l16;
      float rsum = 0.f;
#pragma unroll
      for (int nt = 0; nt < 4; ++nt) {
        float4 ev;
        ev.x = mq[nt][0] ? __expf(acc[mt][nt][0] * SCALEF) : 0.f;
        ev.y = mq[nt][1] ? __expf(acc[mt][nt][1] * SCALEF) : 0.f;
        ev.z = mq[nt][2] ? __expf(acc[mt][nt][2] * SCALEF) : 0.f;
        ev.w = mq[nt][3] ? __expf(acc[mt][nt][3] * SCALEF) : 0.f;
        if (vq[nt])
          *(float4*)(wsCopy + (size_t)row * LSRC + sc[nt]) = ev;
        rsum += (ev.x + ev.y) + (ev.z + ev.w);
      }
      rsum += __shfl_xor(rsum, 16, 64);
      rsum += __shfl_xor(rsum, 32, 64);
      if (lane < 16) atomicAdd(&rowSum[row], rsum);
    }
  }
}

// ---- K5: normalize + scatter (one block owns one output row, 512 thr) -------
__global__ __launch_bounds__(512) void k_norm(const u16* __restrict__ wsE,
                                              const float* __restrict__ wsCopy,
                                              const float* __restrict__ rowSum,
                                              const int* __restrict__ context,
                                              const int* __restrict__ tp,
                                              const int* __restrict__ action,
                                              const int* __restrict__ loc2glo,
                                              float* __restrict__ out) {
  int r = blockIdx.x, b = r >> 7;
  float inv = 1.0f / rowSum[r];
  const uint2* src = (const uint2*)(wsE + (size_t)r * NV);
  float4* dst = (float4*)(out + (size_t)r * NV);
  for (int c = threadIdx.x; c < NV / 4; c += 512) {
    uint2 v = src[c];
    float4 o;
    o.x = __uint_as_float(v.x << 16) * inv;
    o.y = __uint_as_float(v.x & 0xffff0000u) * inv;
    o.z = __uint_as_float(v.y << 16) * inv;
    o.w = __uint_as_float(v.y & 0xffff0000u) * inv;
    dst[c] = o;
  }
  __syncthreads();   // drains stores (vmcnt) so atomics below see them at L2
  int t = threadIdx.x;
  float* op = out + (size_t)r * NV;
  if (t < 256) {
    atomicAdd(op + context[b * 256 + t], wsCopy[r * LSRC + t] * inv);
  } else if (t < 288) {
    int i = t - 256;
    atomicAdd(op + loc2glo[tp[b * 32 + i]], wsCopy[r * LSRC + 256 + i] * inv);
  } else if (t < 320) {
    int i = t - 288;
    atomicAdd(op + loc2glo[action[b * 32 + i]], wsCopy[r * LSRC + 288 + i] * inv);
  }
}

// ---- launch -----------------------------------------------------------------
extern "C" void kernel_launch(void* const* d_in, const int* in_sizes, int n_in,
                              void* d_out, int out_size, void* d_ws, size_t ws_size,
                              hipStream_t stream) {
  const float* dec  = (const float*)d_in[0];
  const float* srch = (const float*)d_in[1];
  const float* Wg   = (const float*)d_in[2];
  const float* bg   = (const float*)d_in[3];
  const int*   mask = (const int*)d_in[4];
  const int*   ctx  = (const int*)d_in[5];
  const int*   tp   = (const int*)d_in[6];
  const int*   act  = (const int*)d_in[7];
  const int*   l2g  = (const int*)d_in[8];
  float* out = (float*)d_out;

  char* ws = (char*)d_ws;
  // ws layout (bytes):
  u16*   Wb      = (u16*)(ws);                    // 32,768,000  bf16 W tiled (125 tiles)
  u16*   wsE     = (u16*)(ws + 32768000);         // 65,536,000  bf16 exp(gen)
  u16*   Ab      = (u16*)(ws + 98304000);         //  1,048,576  bf16 A tiled (4x256 tiles)
  float* wsCopy  = (float*)(ws + 99352576);       //  1,310,720  fp32 exp(copy)
  float* rowSum  = (float*)(ws + 100663296);      //      4,096  fp32 row sums
  u16*   Sb      = (u16*)(ws + 100667392);        //  3,145,728  bf16 srch block-diag tiled

  hipLaunchKernelGGL(k_conv, dim3(1024), dim3(256), 0, stream, dec, srch, Ab, Sb, rowSum);
  hipLaunchKernelGGL(k_convW, dim3(2000), dim3(256), 0, stream, Wg, Wb);
  hipLaunchKernelGGL(k_gemm, dim3(512), dim3(512), 0, stream, Ab, Wb, Sb, bg, mask,
                     wsE, wsCopy, rowSum);
  hipLaunchKernelGGL(k_norm, dim3(MROWS), dim3(512), 0, stream, wsE, wsCopy, rowSum,
                     ctx, tp, act, l2g, out);
}